// Round 1
// baseline (126.060 us; speedup 1.0000x reference)
//
#include <hip/hip_runtime.h>

#define SN 524288   // number of columns in the (64, SN) view of x
// out[i*SN + j] = sum_k A[i][k] * x[k*SN + j],  A = B^{-1} M21

// ---------------- Kernel A: build Ct[c*64 + i] = C[i][c], C = [B | M21] (64 x 128) ---
__global__ __launch_bounds__(256) void k_buildC(const float* __restrict__ L,
                                                const float* __restrict__ R,
                                                float* __restrict__ Ct) {
  // Stage all of L (128x128 f32 = 64 KB) in LDS, XOR-swizzled in float4 units so
  // column reads (lane = row) are bank-conflict-free.
  __shared__ float4 Ls[4096];
  const float4* L4 = (const float4*)L;
  #pragma unroll
  for (int it = 0; it < 16; ++it) {
    int idx = threadIdx.x + it * 256;
    int row = idx >> 5, t4 = idx & 31;
    Ls[(row << 5) + (t4 ^ (row & 7))] = L4[idx];
  }
  __syncthreads();
  int g = blockIdx.x * 256 + threadIdx.x;  // 0..8191
  int c = g >> 6;                          // column of C, uniform per wave
  int i = g & 63;                          // row of C = lane
  if (c < 64) {
    // B[i][c] = 2*(M11 + M22 + R - R^T), M11/M22 diagonals carry +1e-8 each
    float d1 = 0.f, d2 = 0.f;
    #pragma unroll
    for (int t4 = 0; t4 < 32; ++t4) {
      float4 a1 = Ls[(i << 5) + (t4 ^ (i & 7))];          // L[i][4t..]
      float4 b1 = Ls[(c << 5) + (t4 ^ (c & 7))];          // L[c][4t..] (broadcast)
      float4 a2 = Ls[((64 + i) << 5) + (t4 ^ (i & 7))];   // L[64+i][..]
      float4 b2 = Ls[((64 + c) << 5) + (t4 ^ (c & 7))];   // L[64+c][..]
      d1 += a1.x * b1.x + a1.y * b1.y + a1.z * b1.z + a1.w * b1.w;
      d2 += a2.x * b2.x + a2.y * b2.y + a2.z * b2.z + a2.w * b2.w;
    }
    float val = 2.0f * (d1 + d2 + R[i * 64 + c] - R[c * 64 + i]);
    if (i == c) val += 4e-8f;  // 2*(eps + eps) from M11+M22 diagonals
    Ct[c * 64 + i] = val;
  } else {
    int jj = c - 64;  // M21[i][jj] = sum_t L[i][t] * L[64+jj][t]
    float d = 0.f;
    #pragma unroll
    for (int t4 = 0; t4 < 32; ++t4) {
      float4 a = Ls[(i << 5) + (t4 ^ (i & 7))];
      float4 b = Ls[((64 + jj) << 5) + (t4 ^ (jj & 7))];
      d += a.x * b.x + a.y * b.y + a.z * b.z + a.w * b.w;
    }
    Ct[c * 64 + i] = d;
  }
}

// ---------------- Kernel B: Gauss-Jordan solve B A = M21, write At[k*64+i] = A[i][k] ---
// 256 threads: lane r = row, cgrp = which 32-column slice this thread owns in regs.
// Per pivot step only column p (64 f32) and row p (128 f32) go through LDS; parity
// double-buffering gives exactly one __syncthreads per step (race-free: readers of
// buffer b at step p all pass sync(p) before writers of buffer b at step p+2 start).
__global__ __launch_bounds__(256) void k_solve(const float* __restrict__ Ct,
                                               float* __restrict__ At) {
  __shared__ float colbuf[2][64];
  __shared__ __align__(16) float rowbuf[2][128];
  const int r = threadIdx.x & 63;
  const int cgrp = threadIdx.x >> 6;  // 0..3, uniform per wave
  float creg[32];
  #pragma unroll
  for (int cc = 0; cc < 32; ++cc)
    creg[cc] = Ct[(cgrp * 32 + cc) * 64 + r];  // coalesced: lanes r contiguous
  #pragma unroll
  for (int p = 0; p < 64; ++p) {
    const int pb = p & 1, pc = p >> 5, pi = p & 31;
    if (cgrp == pc) colbuf[pb][r] = creg[pi];  // column p (compile-time reg index)
    if (r == p) {
      #pragma unroll
      for (int cc = 0; cc < 32; ++cc) rowbuf[pb][cgrp * 32 + cc] = creg[cc];
    }
    __syncthreads();
    const float f = colbuf[pb][r];
    const float inv = 1.0f / colbuf[pb][p];  // broadcast read
    if (r == p) {
      #pragma unroll
      for (int cc = 0; cc < 32; ++cc) creg[cc] *= inv;
    } else {
      const float gg = f * inv;
      #pragma unroll
      for (int c4 = 0; c4 < 8; ++c4) {
        const float4 pv = *(const float4*)&rowbuf[pb][cgrp * 32 + c4 * 4];
        creg[c4 * 4 + 0] -= gg * pv.x;
        creg[c4 * 4 + 1] -= gg * pv.y;
        creg[c4 * 4 + 2] -= gg * pv.z;
        creg[c4 * 4 + 3] -= gg * pv.w;
      }
    }
  }
  // Right half of C is now A. Write transposed: At[k*64 + i], lanes coalesced.
  if (cgrp >= 2) {
    #pragma unroll
    for (int cc = 0; cc < 32; ++cc) {
      int k = (cgrp - 2) * 32 + cc;
      At[k * 64 + r] = creg[cc];
    }
  }
}

// ---------------- Kernel C: out = A @ X, X = x viewed (64, SN) ------------------------
// One j-column per thread, acc[64] in VGPRs. A fragments come from LDS as uniform
// (broadcast, conflict-free) float4 reads: 1 ds_read_b128 per 4 FMAs.
__global__ __launch_bounds__(256) void k_apply(const float* __restrict__ x,
                                               const float* __restrict__ At,
                                               float* __restrict__ out) {
  __shared__ float4 Al[1024];  // Al[k*16 + i4] = A[4*i4..][k]
  const float4* At4 = (const float4*)At;
  #pragma unroll
  for (int it = 0; it < 4; ++it)
    Al[threadIdx.x + it * 256] = At4[threadIdx.x + it * 256];
  __syncthreads();
  const int j = blockIdx.x * 256 + threadIdx.x;
  float acc[64];
  #pragma unroll
  for (int i = 0; i < 64; ++i) acc[i] = 0.f;
  const float* xp = x + j;
  #pragma unroll 4
  for (int k = 0; k < 64; ++k) {
    const float xv = xp[k * SN];  // dword load, coalesced across the 64 lanes
    #pragma unroll
    for (int i4 = 0; i4 < 16; ++i4) {
      const float4 a = Al[(k << 4) + i4];  // uniform address -> LDS broadcast
      acc[i4 * 4 + 0] += a.x * xv;
      acc[i4 * 4 + 1] += a.y * xv;
      acc[i4 * 4 + 2] += a.z * xv;
      acc[i4 * 4 + 3] += a.w * xv;
    }
  }
  float* op = out + j;
  #pragma unroll
  for (int i = 0; i < 64; ++i) op[i * SN] = acc[i];
}

extern "C" void kernel_launch(void* const* d_in, const int* in_sizes, int n_in,
                              void* d_out, int out_size, void* d_ws, size_t ws_size,
                              hipStream_t stream) {
  const float* x = (const float*)d_in[0];  // 524288 x 64
  const float* L = (const float*)d_in[1];  // 128 x 128
  const float* R = (const float*)d_in[2];  // 64 x 64
  float* out = (float*)d_out;
  float* Ct = (float*)d_ws;        // 128*64 f32 = 32 KB
  float* At = Ct + 128 * 64;       // 64*64 f32 = 16 KB
  k_buildC<<<32, 256, 0, stream>>>(L, R, Ct);
  k_solve<<<1, 256, 0, stream>>>(Ct, At);
  k_apply<<<2048, 256, 0, stream>>>(x, At, out);
}